// Round 11
// baseline (49.984 us; speedup 1.0000x reference)
//
#include <hip/hip_runtime.h>
#include <math.h>

constexpr int T_LEN  = 8192;   // per-row length (== TREF)
constexpr int B_ROWS = 4096;
constexpr int NB     = 49;     // NBINS - 1 bins
constexpr int NC     = 32;     // histogram replicas
constexpr int HDIM   = 32;
constexpr int FBINS  = 8192;   // fine CDF resolution
constexpr int RPB    = 8;      // rows per block (main kernel)
constexpr int RECW   = 52;     // 49 counts + lo + width + pad
constexpr float EPSF = 1e-10f;

// ws layout (float units): [0]=rmin [1]=rmax ; int cdf[FBINS+1] at +8 ;
// float binned[T_LEN] (counting-scattered ref) at +8208
constexpr int WS_CDF_OFF    = 8;
constexpr int WS_BINNED_OFF = 8208;

#define HP(i) ((i) + ((i) >> 5))

// LDS-only block sync: waits DS ops, leaves global/DMA loads in flight.
__device__ __forceinline__ void sync_lds() {
    asm volatile("s_waitcnt lgkmcnt(0)" ::: "memory");
    __builtin_amdgcn_s_barrier();
    __builtin_amdgcn_sched_barrier(0);
}

// -------- kernel 1 (1 block): ref min/max + fine histogram + CDF + scatter ----
__global__ __launch_bounds__(256)
void ref_cdf_kernel(const float* __restrict__ ref, float* __restrict__ wsf) {
    __shared__ float sv[FBINS];
    __shared__ int   hist[HP(FBINS)];
    __shared__ int   wsum[4];
    __shared__ float rmn4[4], rmx4[4];
    const int tid  = threadIdx.x;
    const int lane = tid & 63;
    const int wave = tid >> 6;

    const float4* r4 = (const float4*)ref;
    float4* sv4 = (float4*)sv;
    float mn = 3.0e38f, mx = -3.0e38f;
    #pragma unroll
    for (int i = 0; i < 8; ++i) {
        float4 v = r4[tid + i * 256];
        sv4[tid + i * 256] = v;
        mn = fminf(mn, fminf(fminf(v.x, v.y), fminf(v.z, v.w)));
        mx = fmaxf(mx, fmaxf(fmaxf(v.x, v.y), fmaxf(v.z, v.w)));
    }
    for (int i = tid; i < HP(FBINS); i += 256) hist[i] = 0;
    #pragma unroll
    for (int off = 32; off > 0; off >>= 1) {
        mn = fminf(mn, __shfl_xor(mn, off));
        mx = fmaxf(mx, __shfl_xor(mx, off));
    }
    if (lane == 0) { rmn4[wave] = mn; rmx4[wave] = mx; }
    __syncthreads();
    const float rmin = fminf(fminf(rmn4[0], rmn4[1]), fminf(rmn4[2], rmn4[3]));
    const float rmax = fmaxf(fmaxf(rmx4[0], rmx4[1]), fmaxf(rmx4[2], rmx4[3]));
    const float finv = (float)FBINS / (rmax - rmin);

    for (int i = tid; i < FBINS; i += 256) {
        int fb = min(max((int)((sv[i] - rmin) * finv), 0), FBINS - 1);
        atomicAdd(&hist[HP(fb)], 1);
    }
    __syncthreads();

    const int base = tid * 32;
    int s = 0;
    #pragma unroll
    for (int j = 0; j < 32; ++j) {
        int h = hist[HP(base + j)]; hist[HP(base + j)] = s; s += h;
    }
    const int own = s;
    int incl = s;
    #pragma unroll
    for (int off = 1; off < 64; off <<= 1) {
        int t = __shfl_up(incl, off);
        if (lane >= off) incl += t;
    }
    if (lane == 63) wsum[wave] = incl;
    __syncthreads();
    int woff = 0;
    #pragma unroll
    for (int w = 0; w < 4; ++w) if (w < wave) woff += wsum[w];
    const int add = woff + incl - own;
    #pragma unroll
    for (int j = 0; j < 32; ++j) hist[HP(base + j)] += add;
    __syncthreads();

    int* cdf = (int*)(wsf + WS_CDF_OFF);
    for (int i = tid; i < FBINS; i += 256) cdf[i] = hist[HP(i)];
    if (tid == 0) { cdf[FBINS] = T_LEN; wsf[0] = rmin; wsf[1] = rmax; }
    __syncthreads();

    float* binned = wsf + WS_BINNED_OFF;
    for (int i = tid; i < FBINS; i += 256) {
        float x = sv[i];
        int fb = min(max((int)((x - rmin) * finv), 0), FBINS - 1);
        int pos = atomicAdd(&hist[HP(fb)], 1);
        binned[pos] = x;
    }
}

// -------- kernel 2: DMA double-buffered row pipeline ------------------------
// 512 blocks x 8 rows. Rows staged by global_load_lds into alternating 32KB
// LDS buffers; next row's DMAs are issued BEFORE this row is consumed and
// stay in flight across all barriers (counted vmcnt, LDS-only syncs).
// Each wave stages/reads exclusively its own quarter -> per-wave vmcnt FIFO
// makes s_waitcnt vmcnt(8) an exact "current row staged" condition.
__global__ __launch_bounds__(256, 2)
void kl_pipe_kernel(const float* __restrict__ cur,
                    const float* __restrict__ wsf,
                    const float* __restrict__ w1,
                    const float* __restrict__ b1,
                    const float* __restrict__ w2,
                    const float* __restrict__ b2,
                    float* __restrict__ kl_out,
                    float* __restrict__ enc_out) {
    __shared__ float    buf[2][T_LEN];        // 64 KB
    __shared__ unsigned hq[NC * NB];          // 6272 B
    __shared__ float    scmn[4], scmx[4];
    __shared__ float    rec[RPB][RECW];       // per-row results for the tails

    const int tid  = threadIdx.x;
    const int lane = tid & 63;
    const int wave = tid >> 6;
    const int rbase = blockIdx.x * RPB;
    const float* src = cur + (size_t)rbase * T_LEN;
    const float rmin = wsf[0], rmax = wsf[1];

    // stage one wave-quarter of row r into buf[pbuf]: 8 x 1KB DMAs
    auto stage = [&](int r, int pbuf) {
        const float* g = src + (size_t)r * T_LEN + wave * 2048;
        #pragma unroll
        for (int i = 0; i < 8; ++i) {
            __builtin_amdgcn_global_load_lds(
                (const __attribute__((address_space(1))) void*)(g + i * 256 + lane * 4),
                (__attribute__((address_space(3))) void*)&buf[pbuf][wave * 2048 + i * 256],
                16, 0, 0);
        }
    };

    stage(0, 0);                               // prologue: row 0 in flight

    #pragma unroll
    for (int r = 0; r < RPB; ++r) {
        if (r + 1 < RPB) stage(r + 1, (r + 1) & 1);   // prefetch next row

        // zero histogram while waiting on the DMA
        for (int i = tid; i < NC * NB; i += 256) hq[i] = 0u;

        if (r + 1 < RPB) {
            asm volatile("s_waitcnt vmcnt(8)" ::: "memory");  // row r staged,
        } else {                                              // next 8 in flight
            asm volatile("s_waitcnt vmcnt(0)" ::: "memory");
        }
        __builtin_amdgcn_sched_barrier(0);

        // single LDS read pass: own quarter -> regs
        const float4* b4 = (const float4*)buf[r & 1];
        float4 v[8];
        #pragma unroll
        for (int i = 0; i < 8; ++i) v[i] = b4[wave * 512 + i * 64 + lane];

        float mn = 3.0e38f, mx = -3.0e38f;
        #pragma unroll
        for (int i = 0; i < 8; ++i) {
            mn = fminf(mn, fminf(fminf(v[i].x, v[i].y), fminf(v[i].z, v[i].w)));
            mx = fmaxf(mx, fmaxf(fmaxf(v[i].x, v[i].y), fmaxf(v[i].z, v[i].w)));
        }
        #pragma unroll
        for (int off = 32; off > 0; off >>= 1) {
            mn = fminf(mn, __shfl_xor(mn, off));
            mx = fmaxf(mx, __shfl_xor(mx, off));
        }
        if (lane == 0) { scmn[wave] = mn; scmx[wave] = mx; }
        sync_lds();                            // hq zero + scmn/scmx visible

        const float lo = fminf(rmin,
            fminf(fminf(scmn[0], scmn[1]), fminf(scmn[2], scmn[3])));
        const float hi = fmaxf(rmax,
            fmaxf(fmaxf(scmx[0], scmx[1]), fmaxf(scmx[2], scmx[3])));
        const float width = (hi - lo) / (float)NB;
        const float winv = 1.0f / width, nlw = -lo * winv;

        // bin from regs (lower clamp provably redundant: trunc maps (-1,0)->0)
        unsigned* myq = hq + (tid & (NC - 1)) * NB;
        #pragma unroll
        for (int i = 0; i < 8; ++i) {
            int i0 = min((int)fmaf(v[i].x, winv, nlw), NB - 1);
            int i1 = min((int)fmaf(v[i].y, winv, nlw), NB - 1);
            int i2 = min((int)fmaf(v[i].z, winv, nlw), NB - 1);
            int i3 = min((int)fmaf(v[i].w, winv, nlw), NB - 1);
            atomicAdd(&myq[i0], 1u); atomicAdd(&myq[i1], 1u);
            atomicAdd(&myq[i2], 1u); atomicAdd(&myq[i3], 1u);
        }
        sync_lds();                            // all atomics done

        if (tid < NB) {                        // reduce 32 replicas -> rec
            unsigned sq = 0u;
            #pragma unroll
            for (int c = 0; c < NC; ++c) sq += hq[c * NB + tid];
            rec[r][tid] = (float)sq;           // counts <= 8192: exact in f32
        }
        if (tid == NB)     rec[r][NB]     = lo;
        if (tid == NB + 1) rec[r][NB + 1] = width;
        sync_lds();                            // rec done before hq re-zeroed
    }

    // ---- batched tails: wave w handles rows w and w+4 ----
    for (int rr = wave; rr < RPB; rr += 4) {
        const float lo = rec[rr][NB], width = rec[rr][NB + 1];
        const bool act = lane < NB;
        const float inv = 1.0f / ((float)T_LEN * width);
        float p = 0.0f, q = 0.0f;
        if (act) q = rec[rr][lane] * inv + EPSF;

        int C = T_LEN;
        if (lane < NB - 1) {
            const float kp1  = (float)(lane + 1);
            const float finv = (float)FBINS / (rmax - rmin);
            const int* cdf = (const int*)(wsf + WS_CDF_OFF);
            const float* binned = wsf + WS_BINNED_OFF;
            const float t = fmaf(width, kp1, lo);
            int fb = (int)floorf((t - rmin) * finv);
            int a  = min(max(fb - 2, 0), FBINS);
            int bb = min(max(fb + 3, 0), FBINS);
            int ia = cdf[a], ib = cdf[bb];
            C = ia;
            for (int i = ia; i < ib; i += 4) {
                float x0 = binned[i];
                float x1 = (i + 1 < ib) ? binned[i + 1] : 3.0e38f;
                float x2 = (i + 2 < ib) ? binned[i + 2] : 3.0e38f;
                float x3 = (i + 3 < ib) ? binned[i + 3] : 3.0e38f;
                C += ((x0 - lo) / width < kp1) ? 1 : 0;
                C += ((x1 - lo) / width < kp1) ? 1 : 0;
                C += ((x2 - lo) / width < kp1) ? 1 : 0;
                C += ((x3 - lo) / width < kp1) ? 1 : 0;
            }
        }
        int Cprev = __shfl_up(C, 1);
        if (lane == 0) Cprev = 0;
        if (act) p = (float)(C - Cprev) * inv + EPSF;

        float P = p, Q = q;
        #pragma unroll
        for (int off = 32; off > 0; off >>= 1) {
            P += __shfl_xor(P, off);
            Q += __shfl_xor(Q, off);
        }
        float term = 0.0f;
        if (act) {
            const float pn = p / P;
            const float qn = q / Q;
            term = pn * logf(pn / qn);
        }
        #pragma unroll
        for (int off = 32; off > 0; off >>= 1) term += __shfl_xor(term, off);
        if (lane == 0) kl_out[rbase + rr] = term;

        if (lane < HDIM) {
            float acc = b2[lane];
            #pragma unroll
            for (int t2 = 0; t2 < HDIM; ++t2) {
                float h = fmaxf(fmaf(term, w1[t2], b1[t2]), 0.0f);
                acc = fmaf(h, w2[lane * HDIM + t2], acc);
            }
            enc_out[(size_t)(rbase + rr) * HDIM + lane] = acc;
        }
    }
}

extern "C" void kernel_launch(void* const* d_in, const int* in_sizes, int n_in,
                              void* d_out, int out_size, void* d_ws, size_t ws_size,
                              hipStream_t stream) {
    const float* cur = (const float*)d_in[0];
    const float* ref = (const float*)d_in[1];
    const float* w1  = (const float*)d_in[2];
    const float* b1  = (const float*)d_in[3];
    const float* w2  = (const float*)d_in[4];
    const float* b2  = (const float*)d_in[5];
    float* out = (float*)d_out;           // [0, B) = kl ; [B, B + B*H) = encoded
    float* wsf = (float*)d_ws;

    ref_cdf_kernel<<<1, 256, 0, stream>>>(ref, wsf);
    kl_pipe_kernel<<<B_ROWS / RPB, 256, 0, stream>>>(
        cur, wsf, w1, b1, w2, b2, out, out + B_ROWS);
}